// Round 1
// baseline (36.995 us; speedup 1.0000x reference)
//
#include <hip/hip_runtime.h>

// LJ pairwise energy matrix, N x N fp32 output.
// reference: disp[i,j] = q[j] - q[i], min-image, mask = (j>i) & (r2 < CUT^2),
// energy = 4*eps*((s/r)^12 - (s/r)^6) where mask else 0.

#define NATOMS 6144

__global__ __launch_bounds__(256) void lj_pair_energy(
    const float* __restrict__ q, float* __restrict__ out) {
    constexpr float CELL = 66.0f;
    constexpr float INV_CELL = 1.0f / 66.0f;
    constexpr float SIGMA2 = 3.405f * 3.405f;
    constexpr float EPS4 = 4.0f * 0.0103f;
    constexpr float CUT2 = 9.0f * 9.0f;

    const int i  = blockIdx.y;                       // row (atom i)
    const int j4 = blockIdx.x * blockDim.x + threadIdx.x; // group of 4 cols
    const int j0 = j4 * 4;

    // q[i] — same for whole block; compiler will scalarize/broadcast.
    const float qix = q[i * 3 + 0];
    const float qiy = q[i * 3 + 1];
    const float qiz = q[i * 3 + 2];

    // 4 consecutive atoms j0..j0+3: 12 contiguous floats = 3 float4 loads.
    const float4* qv = reinterpret_cast<const float4*>(q + (size_t)j0 * 3);
    const float4 a = qv[0];
    const float4 b = qv[1];
    const float4 c = qv[2];

    const float xs[4] = {a.x, a.w, b.z, c.y};
    const float ys[4] = {a.y, b.x, b.w, c.z};
    const float zs[4] = {a.z, b.y, c.x, c.w};

    float4 e;
    float* ep = &e.x;
#pragma unroll
    for (int k = 0; k < 4; ++k) {
        float dx = xs[k] - qix;
        float dy = ys[k] - qiy;
        float dz = zs[k] - qiz;
        dx -= CELL * rintf(dx * INV_CELL);
        dy -= CELL * rintf(dy * INV_CELL);
        dz -= CELL * rintf(dz * INV_CELL);
        const float r2 = fmaf(dx, dx, fmaf(dy, dy, dz * dz));
        const bool m = ((j0 + k) > i) && (r2 < CUT2);
        const float sr2 = SIGMA2 / r2;          // inf on diagonal, masked below
        const float sr6 = sr2 * sr2 * sr2;
        const float en = EPS4 * fmaf(sr6, sr6, -sr6);
        ep[k] = m ? en : 0.0f;
    }

    reinterpret_cast<float4*>(out)[(size_t)i * (NATOMS / 4) + j4] = e;
}

extern "C" void kernel_launch(void* const* d_in, const int* in_sizes, int n_in,
                              void* d_out, int out_size, void* d_ws, size_t ws_size,
                              hipStream_t stream) {
    const float* q = (const float*)d_in[0];
    float* out = (float*)d_out;

    dim3 block(256, 1, 1);
    dim3 grid(NATOMS / (4 * 256), NATOMS, 1); // (6, 6144)
    lj_pair_energy<<<grid, block, 0, stream>>>(q, out);
}

// Round 3
// 30.020 us; speedup vs baseline: 1.2323x; 1.2323x over previous
//
#include <hip/hip_runtime.h>

// LJ pairwise energy matrix, N x N fp32 output.
// reference: disp[i,j] = q[j] - q[i], min-image, mask = (j>i) & (r2 < CUT^2),
// energy = 4*eps*((s/r)^12 - (s/r)^6) where mask else 0.
//
// Write-bound: 151 MB output, inputs (72 KB) cache-resident.
// v_rcp_f32 instead of full-precision divide: ~1ulp relative error,
// amplified ~12x through the r^-12 term => ~1e-5 relative, vs ~3e-2
// relative threshold headroom. Keeps VALU under the HBM write time.

#define NATOMS 6144

typedef float f32x4 __attribute__((ext_vector_type(4)));

__global__ __launch_bounds__(256) void lj_pair_energy(
    const float* __restrict__ q, float* __restrict__ out) {
    constexpr float CELL = 66.0f;
    constexpr float INV_CELL = 1.0f / 66.0f;
    constexpr float SIGMA2 = 3.405f * 3.405f;
    constexpr float EPS4 = 4.0f * 0.0103f;
    constexpr float CUT2 = 9.0f * 9.0f;

    const int i  = blockIdx.y;                            // row (atom i)
    const int j4 = blockIdx.x * blockDim.x + threadIdx.x; // group of 4 cols
    const int j0 = j4 * 4;

    // q[i] — wave-uniform; compiler scalarizes.
    const float qix = q[i * 3 + 0];
    const float qiy = q[i * 3 + 1];
    const float qiz = q[i * 3 + 2];

    // 4 consecutive atoms j0..j0+3: 12 contiguous floats = 3 float4 loads.
    const f32x4* qv = reinterpret_cast<const f32x4*>(q + (size_t)j0 * 3);
    const f32x4 a = qv[0];
    const f32x4 b = qv[1];
    const f32x4 c = qv[2];

    const float xs[4] = {a.x, a.w, b.z, c.y};
    const float ys[4] = {a.y, b.x, b.w, c.z};
    const float zs[4] = {a.z, b.y, c.x, c.w};

    f32x4 e;
#pragma unroll
    for (int k = 0; k < 4; ++k) {
        float dx = xs[k] - qix;
        float dy = ys[k] - qiy;
        float dz = zs[k] - qiz;
        dx -= CELL * rintf(dx * INV_CELL);
        dy -= CELL * rintf(dy * INV_CELL);
        dz -= CELL * rintf(dz * INV_CELL);
        const float r2 = fmaf(dx, dx, fmaf(dy, dy, dz * dz));
        const bool m = ((j0 + k) > i) && (r2 < CUT2);
        // fast reciprocal: v_rcp_f32 (single instr, ~1ulp)
        const float sr2 = SIGMA2 * __builtin_amdgcn_rcpf(r2);
        const float sr6 = sr2 * sr2 * sr2;
        const float en = EPS4 * fmaf(sr6, sr6, -sr6);
        e[k] = m ? en : 0.0f;
    }

    __builtin_nontemporal_store(
        e, reinterpret_cast<f32x4*>(out) + (size_t)i * (NATOMS / 4) + j4);
}

extern "C" void kernel_launch(void* const* d_in, const int* in_sizes, int n_in,
                              void* d_out, int out_size, void* d_ws, size_t ws_size,
                              hipStream_t stream) {
    const float* q = (const float*)d_in[0];
    float* out = (float*)d_out;

    dim3 block(256, 1, 1);
    dim3 grid(NATOMS / (4 * 256), NATOMS, 1); // (6, 6144)
    lj_pair_energy<<<grid, block, 0, stream>>>(q, out);
}

// Round 4
// 26.860 us; speedup vs baseline: 1.3773x; 1.1176x over previous
//
#include <hip/hip_runtime.h>

// LJ pairwise energy matrix, N x N fp32 output.
// reference: disp[i,j] = q[j] - q[i], min-image, mask = (j>i) & (r2 < CUT^2),
// energy = 4*eps*((s/r)^12 - (s/r)^6) where mask else 0.
//
// Write-bound: 151 MB output, inputs (72 KB) cache-resident.
// - blocks fully at/below the diagonal (~48%) store zeros and exit (pure write)
// - min-image via d = min(|dx|, 66-|dx|)  (|.| is a free input modifier);
//   differs from rint() path only near |dx|=33 >> cutoff -> masked, safe
// - v_rcp_f32 instead of full-precision divide (~1ulp; output has ~3e-2
//   relative threshold headroom)

#define NATOMS 6144

typedef float f32x4 __attribute__((ext_vector_type(4)));

__global__ __launch_bounds__(256) void lj_pair_energy(
    const float* __restrict__ q, float* __restrict__ out) {
    constexpr float CELL = 66.0f;
    constexpr float SIGMA2 = 3.405f * 3.405f;
    constexpr float EPS4 = 4.0f * 0.0103f;
    constexpr float CUT2 = 9.0f * 9.0f;

    const int i  = blockIdx.y;                            // row (atom i)
    const int j4 = blockIdx.x * blockDim.x + threadIdx.x; // group of 4 cols
    const int j0 = j4 * 4;

    f32x4* const dst =
        reinterpret_cast<f32x4*>(out) + (size_t)i * (NATOMS / 4) + j4;

    // Block's column span is [1024*bx, 1024*bx+1023]. If every j <= i, the
    // whole block is masked (j>i fails) -> pure zero store, no compute.
    if (i >= (int)(blockIdx.x * 1024 + 1023)) {
        __builtin_nontemporal_store((f32x4){0.f, 0.f, 0.f, 0.f}, dst);
        return;
    }

    // q[i] — wave-uniform; compiler scalarizes.
    const float qix = q[i * 3 + 0];
    const float qiy = q[i * 3 + 1];
    const float qiz = q[i * 3 + 2];

    // 4 consecutive atoms j0..j0+3: 12 contiguous floats = 3 float4 loads.
    const f32x4* qv = reinterpret_cast<const f32x4*>(q + (size_t)j0 * 3);
    const f32x4 a = qv[0];
    const f32x4 b = qv[1];
    const f32x4 c = qv[2];

    const float xs[4] = {a.x, a.w, b.z, c.y};
    const float ys[4] = {a.y, b.x, b.w, c.z};
    const float zs[4] = {a.z, b.y, c.x, c.w};

    f32x4 e;
#pragma unroll
    for (int k = 0; k < 4; ++k) {
        // min-image distance per axis: min(|d|, CELL-|d|); abs is a free
        // VOP3 modifier on both consumers.
        const float ax = xs[k] - qix;
        const float ay = ys[k] - qiy;
        const float az = zs[k] - qiz;
        const float dx = fminf(fabsf(ax), CELL - fabsf(ax));
        const float dy = fminf(fabsf(ay), CELL - fabsf(ay));
        const float dz = fminf(fabsf(az), CELL - fabsf(az));
        const float r2 = fmaf(dx, dx, fmaf(dy, dy, dz * dz));
        const bool m = ((j0 + k) > i) && (r2 < CUT2);
        // fast reciprocal: v_rcp_f32 (single instr, ~1ulp)
        const float sr2 = SIGMA2 * __builtin_amdgcn_rcpf(r2);
        const float sr6 = sr2 * sr2 * sr2;
        const float en = EPS4 * fmaf(sr6, sr6, -sr6);
        e[k] = m ? en : 0.0f;
    }

    __builtin_nontemporal_store(e, dst);
}

extern "C" void kernel_launch(void* const* d_in, const int* in_sizes, int n_in,
                              void* d_out, int out_size, void* d_ws, size_t ws_size,
                              hipStream_t stream) {
    const float* q = (const float*)d_in[0];
    float* out = (float*)d_out;

    dim3 block(256, 1, 1);
    dim3 grid(NATOMS / (4 * 256), NATOMS, 1); // (6, 6144)
    lj_pair_energy<<<grid, block, 0, stream>>>(q, out);
}

// Round 5
// 26.485 us; speedup vs baseline: 1.3968x; 1.0142x over previous
//
#include <hip/hip_runtime.h>

// LJ pairwise energy matrix, N x N fp32 output.
// reference: disp[i,j] = q[j] - q[i], min-image, mask = (j>i) & (r2 < CUT^2),
// energy = 4*eps*((s/r)^12 - (s/r)^6) where mask else 0.
//
// Write-bound: 151 MB output at ~6.7 TB/s achievable write BW => 22.3 us floor.
// - 2 rows per thread: shared j-atom loads, half the waves, row-paired FMA
//   chains pack into v_pk_fma_f32
// - per-wave (256-col) zero-skip of the lower triangle (~48% of matrix is
//   pure zero-store, runs at fill speed)
// - min-image via d = min(|dx|, 66-|dx|) (abs is a free VOP3 modifier);
//   differs from the rint() path only near |dx|=33 >> cutoff -> masked, safe
// - v_rcp_f32 instead of full-precision divide (~1ulp; ~3e-2 relative
//   threshold headroom)

#define NATOMS 6144

typedef float f32x4 __attribute__((ext_vector_type(4)));

__global__ __launch_bounds__(256) void lj_pair_energy(
    const float* __restrict__ q, float* __restrict__ out) {
    constexpr float CELL = 66.0f;
    constexpr float SIGMA2 = 3.405f * 3.405f;
    constexpr float EPS4 = 4.0f * 0.0103f;
    constexpr float CUT2 = 9.0f * 9.0f;

    const int i0 = blockIdx.y * 2;                        // rows i0, i0+1
    const int i1 = i0 + 1;
    const int t  = blockIdx.x * blockDim.x + threadIdx.x; // col group (4 cols)
    const int j0 = t * 4;

    f32x4* const dst0 =
        reinterpret_cast<f32x4*>(out) + (size_t)i0 * (NATOMS / 4) + t;
    f32x4* const dst1 = dst0 + (NATOMS / 4);

    // Wave-uniform: last column covered by this wave's 64 lanes (256 cols).
    const int waveLastJ = (((int)(threadIdx.x & ~63u) + (int)blockIdx.x * 256) + 64) * 4 - 1;

    // all j in the wave span <= i0  =>  both rows fully masked: pure write.
    // (i0 >= waveLastJ implies i1 >= waveLastJ.)
    if (i0 >= waveLastJ) {
        const f32x4 z = {0.f, 0.f, 0.f, 0.f};
        __builtin_nontemporal_store(z, dst0);
        __builtin_nontemporal_store(z, dst1);
        return;
    }

    // q[i0], q[i1] — wave-uniform scalar loads.
    const float q0x = q[i0 * 3 + 0], q0y = q[i0 * 3 + 1], q0z = q[i0 * 3 + 2];
    const float q1x = q[i1 * 3 + 0], q1y = q[i1 * 3 + 1], q1z = q[i1 * 3 + 2];

    // 4 consecutive atoms j0..j0+3: 12 contiguous floats = 3 float4 loads,
    // shared by both rows.
    const f32x4* qv = reinterpret_cast<const f32x4*>(q + (size_t)j0 * 3);
    const f32x4 a = qv[0];
    const f32x4 b = qv[1];
    const f32x4 c = qv[2];

    const float xs[4] = {a.x, a.w, b.z, c.y};
    const float ys[4] = {a.y, b.x, b.w, c.z};
    const float zs[4] = {a.z, b.y, c.x, c.w};

    f32x4 e0, e1;
#pragma unroll
    for (int k = 0; k < 4; ++k) {
        const int j = j0 + k;
        // row 0
        {
            const float ax = xs[k] - q0x;
            const float ay = ys[k] - q0y;
            const float az = zs[k] - q0z;
            const float dx = fminf(fabsf(ax), CELL - fabsf(ax));
            const float dy = fminf(fabsf(ay), CELL - fabsf(ay));
            const float dz = fminf(fabsf(az), CELL - fabsf(az));
            const float r2 = fmaf(dx, dx, fmaf(dy, dy, dz * dz));
            const bool m = (j > i0) && (r2 < CUT2);
            const float sr2 = SIGMA2 * __builtin_amdgcn_rcpf(r2);
            const float sr6 = sr2 * sr2 * sr2;
            const float en = EPS4 * fmaf(sr6, sr6, -sr6);
            e0[k] = m ? en : 0.0f;
        }
        // row 1
        {
            const float ax = xs[k] - q1x;
            const float ay = ys[k] - q1y;
            const float az = zs[k] - q1z;
            const float dx = fminf(fabsf(ax), CELL - fabsf(ax));
            const float dy = fminf(fabsf(ay), CELL - fabsf(ay));
            const float dz = fminf(fabsf(az), CELL - fabsf(az));
            const float r2 = fmaf(dx, dx, fmaf(dy, dy, dz * dz));
            const bool m = (j > i1) && (r2 < CUT2);
            const float sr2 = SIGMA2 * __builtin_amdgcn_rcpf(r2);
            const float sr6 = sr2 * sr2 * sr2;
            const float en = EPS4 * fmaf(sr6, sr6, -sr6);
            e1[k] = m ? en : 0.0f;
        }
    }

    __builtin_nontemporal_store(e0, dst0);
    __builtin_nontemporal_store(e1, dst1);
}

extern "C" void kernel_launch(void* const* d_in, const int* in_sizes, int n_in,
                              void* d_out, int out_size, void* d_ws, size_t ws_size,
                              hipStream_t stream) {
    const float* q = (const float*)d_in[0];
    float* out = (float*)d_out;

    dim3 block(256, 1, 1);
    dim3 grid(NATOMS / (4 * 256), NATOMS / 2, 1); // (6, 3072)
    lj_pair_energy<<<grid, block, 0, stream>>>(q, out);
}